// Round 9
// baseline (213.351 us; speedup 1.0000x reference)
//
#include <hip/hip_runtime.h>
#include <stdint.h>

#define NB 32768
#define NPASS 4
#define FULL27 0x07FFFFFFu
#define PUZ_PER_BLK 64            // 64 puzzles/block (16 per wave, 4 lanes each)
#define SOLVE_BLKS (NB / PUZ_PER_BLK)   // 512 blocks x 256 threads = 2048 waves
#define BLK_DW 1458               // 64*729/32 dwords of bits per block (exact)
#define BLK_V4 11664              // 64*729/4 float4s per block (exact)
#define NCHUNK 12                 // 12 chunks x 1024 float4 (last partial, clamped)

// Per-band bitboard: digit d, band b (rows 3b..3b+2), bit (r*9+c).
// BOX k mask within band: 0x1C0E07 << 3k ; COL c: 0x40201 << c ; ROW r: 0x1FF << 9r
// Flat float layout: puzzle p, digit d, band b, cell j == p*729 + d*81 + b*27 + j.
// Pool layout: bit j of block pool == float blk*46656 + j.
//
// SESSION LEDGER:
//   r15 (216.5us): 3 lanes/puzzle single kernel, ds_bpermute. kernel 107us.
//   r16 (213.5us): quad DPP bands. LDS_CONF 3.0M->192K, VALUBusy 42->55.
//   r17 (241.6us REGRESSION): solve at 512 waves -> half the SIMDs empty.
//   r18/r20 (216.2us): split. Solve 72us @ VALUBusy 73-75%. Pack+gap ~34us.
//   r21 (215.6us): fused coalesced DPP pack. Kernel 104; pack = 32us stall,
//     VGPR=48 -> loads serialized, 1 outstanding/wave.
//   r22 (209.7us): +launch_bounds(256,2)+src ping-pong: VGPR STILL 48 —
//     compiler collapses reg double-buffers. kernel 101.6.
//   r23 (207.2us): +sched_barrier fences: VGPR STILL 48, profiled kernel 142
//     (VALUBusy 39) — SB pinning defeats the scheduler (m141 failure mode).
//     CONCLUSION: VGPR-resident pipelining unachievable at source level.
//   r24 (this): pack via global_load_lds width=16 (VMEM->LDS queue holds the
//     in-flight data, zero VGPR cost, compiler can't collapse). 3-buffer LDS
//     ring, counted s_waitcnt vmcnt(4) (chunk c+1 stays in flight while
//     processing c), per-wave-private staging (no barriers in pack loop).
//     Predict pack ~15us, kernel ~88, total ~195.

__device__ __forceinline__ uint32_t colfold(uint32_t w) {
    return (w | (w >> 9) | (w >> 18)) & 0x1FFu;
}
__device__ __forceinline__ uint32_t colmaj2(uint32_t w) {   // columns with >=2 bits in band
    return ((w & (w >> 9)) | ((w | (w >> 9)) & (w >> 18))) & 0x1FFu;
}
// quad_perm rotations within the 4-lane quad: band b reads band (b+1)%3 / (b-1)%3.
// ctrl = sel0 | sel1<<2 | sel2<<4 | sel3<<6 : [1,2,0,0]=0x09 ; [2,0,1,0]=0x12
__device__ __forceinline__ uint32_t rotA(uint32_t v) {      // from band+1 (mod 3)
    return (uint32_t)__builtin_amdgcn_update_dpp(0, (int)v, 0x09, 0xF, 0xF, true);
}
__device__ __forceinline__ uint32_t rotB(uint32_t v) {      // from band-1 (mod 3)
    return (uint32_t)__builtin_amdgcn_update_dpp(0, (int)v, 0x12, 0xF, 0xF, true);
}
// pack-tree swaps: quad_perm [1,0,3,2]=0xB1 (lane^1), [2,3,0,1]=0x4E (lane^2)
__device__ __forceinline__ uint32_t dppx1(uint32_t v) {
    return (uint32_t)__builtin_amdgcn_update_dpp(0, (int)v, 0xB1, 0xF, 0xF, true);
}
__device__ __forceinline__ uint32_t dppx2(uint32_t v) {
    return (uint32_t)__builtin_amdgcn_update_dpp(0, (int)v, 0x4E, 0xF, 0xF, true);
}

__global__ __launch_bounds__(256, 2)
void sudoku_kernel(const uint32_t* __restrict__ in, float* __restrict__ out,
                   float* __restrict__ solved) {
    __shared__ uint32_t pool[BLK_DW + 2];   // 46656 bits (+pad for extract's 64b read)
    __shared__ uint4 stage[3][1024];        // 48KB float4 staging ring (3 x 16KB)
    const int tid = threadIdx.x;
    const int q = tid >> 2;                 // puzzle slot 0..63
    const int band = tid & 3;               // 0..2 live, 3 idle in solve
    const int w = tid >> 6;                 // wave 0..3
    const int lane = tid & 63;
    const int P0 = blockIdx.x * PUZ_PER_BLK;

    // ---------------- PACK: global_load_lds ring -> DPP nibble pack -> pool ----
    // Chunk c = float4s [c*1024, c*1024+1024); wave w stages & processes its own
    // quarter [w*256, w*256+256) via 4x global_load_lds_dwordx4 (lane-contiguous,
    // dest = ring buf + w*256+i*64, lane l lands at +l). Counted vmcnt(4) keeps
    // chunk c+1's loads in flight while packing chunk c (no VGPR cost - the
    // VMEM->LDS queue holds the data; r21-r23 showed reg-dbuf is uncollapsible).
    // 3-buffer ring: proc(c) reads c%3, c+1 lands in (c+1)%3, issue targets
    // (c+2)%3 -> no WAR overlap, no barriers (waves touch only their quarter).
    {
        const uint4* src4 = (const uint4*)in + (size_t)blockIdx.x * BLK_V4;
        uint16_t* hp = (uint16_t*)pool;

        #define ISSUE(c)                                                          \
            { _Pragma("unroll")                                                   \
              for (int i = 0; i < 4; ++i) {                                       \
                  int g = (c) * 1024 + w * 256 + i * 64 + lane;                   \
                  if (g > BLK_V4 - 1) g = BLK_V4 - 1;                             \
                  __builtin_amdgcn_global_load_lds(                               \
                      (const __attribute__((address_space(1))) void*)(src4 + g),  \
                      (__attribute__((address_space(3))) void*)                   \
                          &stage[(c) % 3][w * 256 + i * 64],                      \
                      16, 0, 0);                                                  \
              } }

        ISSUE(0);
        ISSUE(1);
        #pragma unroll
        for (int c = 0; c < NCHUNK; ++c) {
            if (c < NCHUNK - 1) asm volatile("s_waitcnt vmcnt(4)" ::: "memory");
            else                asm volatile("s_waitcnt vmcnt(0)" ::: "memory");
            __builtin_amdgcn_sched_barrier(0);
            #pragma unroll
            for (int j = 0; j < 4; ++j) {
                uint4 v = stage[c % 3][w * 256 + j * 64 + lane];
                // inputs are exactly 0.0f/1.0f -> bit 23 of the pattern is the flag
                uint32_t n = ((v.x >> 23) & 1u) | ((v.y >> 22) & 2u)
                           | ((v.z >> 21) & 4u) | ((v.w >> 20) & 8u);
                uint32_t b = n | (dppx1(n) << 4);   // byte, valid on even lanes
                uint32_t h = b | (dppx2(b) << 8);   // u16, valid on lane%4==0
                if ((lane & 3) == 0) {
                    int t = (c * 1024 + w * 256 + j * 64 + lane) >> 2;
                    if (t < 2 * BLK_DW) hp[t] = (uint16_t)h;
                }
            }
            if (c < NCHUNK - 2) ISSUE(c + 2);
        }
        #undef ISSUE
    }
    __syncthreads();

    // ---- extract 9 band-words for this lane (band 3 reads in-bounds garbage)
    uint32_t bd[9];
    {
        const int bb0 = q * 729 + band * 27;
        #pragma unroll
        for (int d = 0; d < 9; ++d) {
            int bit = bb0 + d * 81;
            int di = bit >> 5, sh = bit & 31;
            uint64_t both = (uint64_t)pool[di] | ((uint64_t)pool[di + 1] << 32);
            bd[d] = (uint32_t)(both >> sh) & FULL27;
        }
    }
    __syncthreads();    // extraction done before pool reuse for expand

    // ---------------- SOLVE (r16/r20-validated quad-DPP logic, unchanged) ------
    #pragma unroll 1
    for (int pass = 0; pass < NPASS; ++pass) {
        // ---------- filter 'box' (band-local) ----------
        {
            uint32_t on = 0, tw = 0, fo = 0;
            #pragma unroll
            for (int d = 0; d < 9; ++d) {
                uint32_t c = on & bd[d];
                on ^= bd[d]; fo |= tw & c; tw ^= c;
            }
            uint32_t ex1 = on & ~tw & ~fo;
            #pragma unroll
            for (int d = 0; d < 9; ++d) {
                uint32_t s = bd[d] & ex1;
                #pragma unroll
                for (int k = 0; k < 3; ++k) {
                    uint32_t bm = 0x1C0E07u << (3 * k);
                    uint32_t sm = s & bm;
                    uint32_t multi = sm & (sm - 1u);
                    uint32_t keep = (sm == 0u) ? 0xFFFFFFFFu : (~bm | (multi ? 0u : sm));
                    bd[d] &= keep;
                }
            }
        }

        // ---------- pointing 'h' (band-local) ----------
        #pragma unroll
        for (int d = 0; d < 9; ++d) {
            uint32_t ww = bd[d];
            uint32_t t = (ww | (ww >> 1) | (ww >> 2)) & 0x01249249u;
            uint32_t sum = (t & 0x1FFu) + ((t >> 9) & 0x1FFu) + ((t >> 18) & 0x1FFu);
            uint32_t single = sum & ~(sum >> 1) & 0x49u;
            uint32_t point = t & (single * 0x40201u);
            uint32_t clearm = 0;
            #pragma unroll
            for (int r = 0; r < 3; ++r) {
                uint32_t pr = (point >> (9 * r)) & 0x1FFu;
                uint32_t multi = pr & (pr - 1u);
                uint32_t segkeep = multi ? 0u : pr * 7u;
                uint32_t rc = pr ? ((0x1FFu & ~segkeep) << (9 * r)) : 0u;
                clearm |= rc;
            }
            bd[d] = ww & ~clearm;
        }

        // ---------- pointing 'v' (cross-band via DPP) ----------
        {
            uint32_t pnt[9];
            #pragma unroll
            for (int d = 0; d < 9; ++d) {
                uint32_t ww = bd[d];
                uint32_t qq = colfold(ww);
                uint32_t u = (qq & 0x49u) + ((qq >> 1) & 0x49u) + ((qq >> 2) & 0x49u);
                uint32_t single = u & ~(u >> 1) & 0x49u;
                pnt[d] = qq & (single * 7u);
            }
            #pragma unroll
            for (int d = 0; d < 9; ++d) {
                uint32_t o = rotA(pnt[d]) | rotB(pnt[d]);
                bd[d] &= ~(o * 0x40201u);
            }
        }

        // ---------- unique 'h' (band-local) ----------
        {
            uint32_t hid[9], has = 0;
            #pragma unroll
            for (int d = 0; d < 9; ++d) {
                uint32_t ww = bd[d], h = 0;
                #pragma unroll
                for (int r = 0; r < 3; ++r) {
                    uint32_t x = ww & (0x1FFu << (9 * r));
                    h |= (x & (x - 1u)) ? 0u : x;
                }
                hid[d] = h; has |= h;
            }
            #pragma unroll
            for (int d = 0; d < 9; ++d) bd[d] = (bd[d] & ~has) | hid[d];
        }

        // ---------- unique 'v' (cross-band via DPP) ----------
        {
            uint32_t hid[9], has = 0;
            #pragma unroll
            for (int d = 0; d < 9; ++d) {
                uint32_t ww = bd[d];
                uint32_t q0 = colfold(ww), m0 = colmaj2(ww);
                uint32_t ex = q0 | (m0 << 9);
                uint32_t ea = rotA(ex);
                uint32_t eb = rotB(ex);
                uint32_t qa = ea & 0x1FFu, ma = ea >> 9;
                uint32_t qb = eb & 0x1FFu, mb = eb >> 9;
                uint32_t ge2 = m0 | ma | mb | (q0 & qa) | (q0 & qb) | (qa & qb);
                uint32_t ex1c = (q0 | qa | qb) & ~ge2;   // column total count == 1
                hid[d] = ww & ((ex1c & q0) * 0x40201u);
                has |= hid[d];
            }
            #pragma unroll
            for (int d = 0; d < 9; ++d) bd[d] = (bd[d] & ~has) | hid[d];
        }

        // ---------- unique 'box' (band-local) ----------
        {
            uint32_t hid[9], has = 0;
            #pragma unroll
            for (int d = 0; d < 9; ++d) {
                uint32_t ww = bd[d], h = 0;
                #pragma unroll
                for (int k = 0; k < 3; ++k) {
                    uint32_t x = ww & (0x1C0E07u << (3 * k));
                    h |= (x & (x - 1u)) ? 0u : x;
                }
                hid[d] = h; has |= h;
            }
            #pragma unroll
            for (int d = 0; d < 9; ++d) bd[d] = (bd[d] & ~has) | hid[d];
        }

        // ---------- doubles 'v' twice (cross-band via DPP) ----------
        #pragma unroll 1
        for (int rep = 0; rep < 2; ++rep) {
            uint32_t on = 0, tw = 0, fo = 0;
            #pragma unroll
            for (int d = 0; d < 9; ++d) {
                uint32_t c = on & bd[d];
                on ^= bd[d]; fo |= tw & c; tw ^= c;
            }
            uint32_t ex2 = tw & ~on & ~fo;
            uint32_t Q[9], K[9];
            #pragma unroll
            for (int d = 0; d < 9; ++d) { Q[d] = bd[d] & ex2; K[d] = 0u; }
            #pragma unroll
            for (int d1 = 0; d1 < 9; ++d1)
                #pragma unroll
                for (int d2 = d1 + 1; d2 < 9; ++d2) {
                    uint32_t P = Q[d1] & Q[d2];
                    uint32_t f0 = colfold(P), g0 = colmaj2(P);
                    uint32_t ex = f0 | (g0 << 9);
                    uint32_t ea = rotA(ex);
                    uint32_t eb = rotB(ex);
                    uint32_t fa = ea & 0x1FFu, ga = ea >> 9;
                    uint32_t fb = eb & 0x1FFu, gb = eb >> 9;
                    // columns with >=2 exact-pair cells across the full column
                    uint32_t dup = g0 | ga | gb | (f0 & fa) | (f0 & fb) | (fa & fb);
                    uint32_t sK = P & (dup * 0x40201u);
                    K[d1] |= sK; K[d2] |= sK;
                }
            #pragma unroll
            for (int d = 0; d < 9; ++d) {
                uint32_t kc = colfold(K[d]);
                uint32_t cols = kc | rotA(kc) | rotB(kc);
                uint32_t em = cols * 0x40201u;
                bd[d] = (bd[d] & ~em) | K[d];
            }
        }

        // ---------- doubles 'box' (band-local) ----------
        {
            uint32_t on = 0, tw = 0, fo = 0;
            #pragma unroll
            for (int d = 0; d < 9; ++d) {
                uint32_t c = on & bd[d];
                on ^= bd[d]; fo |= tw & c; tw ^= c;
            }
            uint32_t ex2 = tw & ~on & ~fo;
            uint32_t Q[9], K[9];
            #pragma unroll
            for (int d = 0; d < 9; ++d) { Q[d] = bd[d] & ex2; K[d] = 0u; }
            #pragma unroll
            for (int d1 = 0; d1 < 9; ++d1)
                #pragma unroll
                for (int d2 = d1 + 1; d2 < 9; ++d2) {
                    uint32_t P = Q[d1] & Q[d2];
                    #pragma unroll
                    for (int k = 0; k < 3; ++k) {
                        uint32_t m = P & (0x1C0E07u << (3 * k));
                        uint32_t s = (m & (m - 1u)) ? m : 0u;
                        K[d1] |= s; K[d2] |= s;
                    }
                }
            #pragma unroll
            for (int d = 0; d < 9; ++d)
                #pragma unroll
                for (int k = 0; k < 3; ++k) {
                    uint32_t bm = 0x1C0E07u << (3 * k);
                    uint32_t t = K[d] & bm;
                    uint32_t mask = t ? (~bm | t) : 0xFFFFFFFFu;
                    bd[d] &= mask;
                }
        }
    } // passes

    // ---------------- solved flag (AND across quad via DPP) ----------------
    {
        uint32_t on = 0, tw = 0, fo = 0;
        #pragma unroll
        for (int d = 0; d < 9; ++d) {
            uint32_t c = on & bd[d];
            on ^= bd[d]; fo |= tw & c; tw ^= c;
        }
        uint32_t okb = ((on & ~tw & ~fo) == FULL27) ? 1u : 0u;
        uint32_t all = okb & rotA(okb) & rotB(okb);
        if (band == 0) solved[P0 + q] = all ? 1.0f : 0.0f;
    }

    // ---------------- EXPAND: repack to pool bitstream -> float4 stores --------
    for (int j = tid; j < BLK_DW + 2; j += 256) pool[j] = 0u;
    __syncthreads();
    if (band != 3) {
        const int pbit = q * 729;
        #pragma unroll
        for (int d = 0; d < 9; ++d) {
            int bitbase = pbit + d * 81 + band * 27;
            int di = bitbase >> 5;
            int sh = bitbase & 31;
            uint64_t both = (uint64_t)bd[d] << sh;
            atomicOr(&pool[di], (uint32_t)both);
            atomicOr(&pool[di + 1], (uint32_t)(both >> 32));
        }
    }
    __syncthreads();
    {
        float4* dst4 = (float4*)(out + (size_t)P0 * 729);  // 46656*blk floats: aligned
        #pragma unroll 4
        for (int i = 0; i < 46; ++i) {                     // 11664 float4s / 256 lanes
            int j = i * 256 + tid;
            if (j < 11664) {
                uint32_t nib = (pool[j >> 3] >> ((j & 7) * 4)) & 0xFu;
                dst4[j] = make_float4((float)(nib & 1u), (float)((nib >> 1) & 1u),
                                      (float)((nib >> 2) & 1u), (float)((nib >> 3) & 1u));
            }
        }
    }
}

extern "C" void kernel_launch(void* const* d_in, const int* in_sizes, int n_in,
                              void* d_out, int out_size, void* d_ws, size_t ws_size,
                              hipStream_t stream) {
    const uint32_t* in = (const uint32_t*)d_in[0];   // float32 bits; 0.0f / 1.0f
    float* out = (float*)d_out;
    float* solved = out + (size_t)NB * 729;
    // single kernel: 512 blocks x 256 threads (2 blocks/CU, 8 waves/CU)
    sudoku_kernel<<<SOLVE_BLKS, 256, 0, stream>>>(in, out, solved);
}